// Round 3
// baseline (107.948 us; speedup 1.0000x reference)
//
#include <hip/hip_runtime.h>

// left/right: [B=4, C=32, H=64, W=128] fp32 ; out: [B, 2C=64, D=48, H, W] fp32
#define BB 4
#define CC 32
#define HH 64
#define WW 128
#define DD 48
#define PLANE (HH * WW)   // 8192 floats = 32 KB

// One block per output plane (b, c2, d): writes 32 KB fully sequentially.
// Grid = B*2C*D = 12288 blocks. XCD-aware swizzle: blocks dispatch round-robin
// across 8 XCDs (block i -> XCD i%8), so we decode blockIdx such that each
// XCD's stream processes one (b,c2) group's 48 d-planes consecutively ->
// the 32 KB input plane is fetched from HBM once and L2-hits 47 times, and
// the XCD's writes form contiguous 1.5 MB runs.
__global__ __launch_bounds__(256) void cost_vol_kernel(
    const float* __restrict__ left,
    const float* __restrict__ right,
    float* __restrict__ out)
{
    const int i   = blockIdx.x;
    const int xcd = i & 7;
    const int j   = i >> 3;          // position within this XCD's stream, 0..1535
    const int gw  = j / DD;          // group-within-XCD, 0..31
    const int d   = j - gw * DD;     // 0..47
    const int g   = (gw << 3) | xcd; // global group = b*64 + c2, 0..255
    const int b   = g >> 6;
    const int c2  = g & 63;

    const bool is_left = (c2 < CC);
    const int  c       = is_left ? c2 : (c2 - CC);
    const float* plane = (is_left ? left : right) + (size_t)(b * CC + c) * PLANE;
    float*       op    = out + ((size_t)g * DD + d) * PLANE;

    const int t  = threadIdx.x;
    const int w0 = (t << 2) & 127;   // column of this thread's float4 (const over k)

    if (is_left) {
        #pragma unroll
        for (int k = 0; k < 8; ++k) {
            const int off = (k << 10) + (t << 2);        // sequential across block
            float4 v = *reinterpret_cast<const float4*>(plane + off);
            v.x = (w0     >= d) ? v.x : 0.0f;
            v.y = (w0 + 1 >= d) ? v.y : 0.0f;
            v.z = (w0 + 2 >= d) ? v.z : 0.0f;
            v.w = (w0 + 3 >= d) ? v.w : 0.0f;
            *reinterpret_cast<float4*>(op + off) = v;
        }
    } else {
        #pragma unroll
        for (int k = 0; k < 8; ++k) {
            const int off = (k << 10) + (t << 2);
            const int e   = off - d;                     // h*128 + (w0 - d)
            const int x0 = e     < 0 ? 0 : e;
            const int x1 = e + 1 < 0 ? 0 : e + 1;
            const int x2 = e + 2 < 0 ? 0 : e + 2;
            const int x3 = e + 3 < 0 ? 0 : e + 3;
            const float r0 = plane[x0];
            const float r1 = plane[x1];
            const float r2 = plane[x2];
            const float r3 = plane[x3];
            float4 v;
            v.x = (w0     >= d) ? r0 : 0.0f;
            v.y = (w0 + 1 >= d) ? r1 : 0.0f;
            v.z = (w0 + 2 >= d) ? r2 : 0.0f;
            v.w = (w0 + 3 >= d) ? r3 : 0.0f;
            *reinterpret_cast<float4*>(op + off) = v;
        }
    }
}

extern "C" void kernel_launch(void* const* d_in, const int* in_sizes, int n_in,
                              void* d_out, int out_size, void* d_ws, size_t ws_size,
                              hipStream_t stream) {
    const float* left  = (const float*)d_in[0];
    const float* right = (const float*)d_in[1];
    float* out = (float*)d_out;

    const int grid  = BB * 2 * CC * DD;   // 12288
    const int block = 256;
    cost_vol_kernel<<<grid, block, 0, stream>>>(left, right, out);
}

// Round 5
// 73.984 us; speedup vs baseline: 1.4591x; 1.4591x over previous
//
#include <hip/hip_runtime.h>

// left/right: [B=4, C=32, H=64, W=128] fp32 ; out: [B, 2C=64, D=48, H, W] fp32
#define BB 4
#define CC 32
#define HH 64
#define WW 128
#define DD 48
#define HT 16                 // h-rows per block
#define RSTRIDE 160           // swizzled LDS row stride (128 dwords -> max slot 158)

typedef float f32x4 __attribute__((ext_vector_type(4)));   // native vec for nontemporal

// Block = 512 threads = (h_loc 0..15) x (w4 0..31). Grid = B*C*(H/HT) = 512.
// Each block stages its 16 right rows in LDS ONCE (input HBM traffic stays
// ~8 MB total), keeps the left float4 in registers, then loops d=0..47
// emitting 8 KB contiguous left + 8 KB contiguous right per iteration.
// Swizzle slot = i + (i>>2): lanes gather dwords at stride 4 -> slot stride 5,
// gcd(5,32)=1 -> all 32 banks; the two h-rows per wave alias 2-way (free).
// Output uses nontemporal stores: write-once stream, don't allocate in L2.
__global__ __launch_bounds__(512) void cost_vol_kernel(
    const float* __restrict__ left,
    const float* __restrict__ right,
    float* __restrict__ out)
{
    __shared__ float lds_r[HT][RSTRIDE];

    const int bx = blockIdx.x;
    const int hq = bx & 3;            // H/HT = 4
    const int c  = (bx >> 2) & 31;    // C = 32
    const int b  = bx >> 7;           // B = 4
    const int h0 = hq * HT;

    const int t     = threadIdx.x;
    const int w4    = t & 31;
    const int h_loc = t >> 5;         // 0..15
    const int w0    = w4 << 2;

    // ---- stage: 16 right rows -> swizzled LDS (one float4 per thread) ------
    {
        const int row = t >> 5;       // 0..15
        const int i0  = (t & 31) << 2;
        const float* rrow = right + (((b * CC + c) * HH) + h0 + row) * WW;
        float4 rv = *reinterpret_cast<const float4*>(rrow + i0);
        lds_r[row][(i0    ) + ((i0    ) >> 2)] = rv.x;
        lds_r[row][(i0 + 1) + ((i0 + 1) >> 2)] = rv.y;
        lds_r[row][(i0 + 2) + ((i0 + 2) >> 2)] = rv.z;
        lds_r[row][(i0 + 3) + ((i0 + 3) >> 2)] = rv.w;
    }

    // left float4 in registers for all 48 d
    const float* lrow = left + (((b * CC + c) * HH) + h0 + h_loc) * WW;
    const float4 lv = *reinterpret_cast<const float4*>(lrow + w0);

    __syncthreads();

    const float* rl = lds_r[h_loc];

    // out[b][c2][d][h][w]; per d the block writes h0..h0+15 = 8 KB contiguous
    float* pL = out + ((((size_t)(b * 2 * CC + c) * DD) * HH) + h0 + h_loc) * WW + w0;
    float* pR = pL + (size_t)CC * DD * HH * WW;   // c2 = c + CC

    #pragma unroll 6
    for (int d = 0; d < DD; ++d) {
        const int e = w0 - d;

        const int i0 = e;     const int x0 = i0 < 0 ? 0 : i0;
        const int i1 = e + 1; const int x1 = i1 < 0 ? 0 : i1;
        const int i2 = e + 2; const int x2 = i2 < 0 ? 0 : i2;
        const int i3 = e + 3; const int x3 = i3 < 0 ? 0 : i3;
        const float r0 = rl[x0 + (x0 >> 2)];
        const float r1 = rl[x1 + (x1 >> 2)];
        const float r2 = rl[x2 + (x2 >> 2)];
        const float r3 = rl[x3 + (x3 >> 2)];

        f32x4 vl, vr;
        vl.x = (i0 >= 0) ? lv.x : 0.0f;  vr.x = (i0 >= 0) ? r0 : 0.0f;
        vl.y = (i1 >= 0) ? lv.y : 0.0f;  vr.y = (i1 >= 0) ? r1 : 0.0f;
        vl.z = (i2 >= 0) ? lv.z : 0.0f;  vr.z = (i2 >= 0) ? r2 : 0.0f;
        vl.w = (i3 >= 0) ? lv.w : 0.0f;  vr.w = (i3 >= 0) ? r3 : 0.0f;

        __builtin_nontemporal_store(vl, reinterpret_cast<f32x4*>(pL));
        __builtin_nontemporal_store(vr, reinterpret_cast<f32x4*>(pR));

        pL += HH * WW;   // next d-plane
        pR += HH * WW;
    }
}

extern "C" void kernel_launch(void* const* d_in, const int* in_sizes, int n_in,
                              void* d_out, int out_size, void* d_ws, size_t ws_size,
                              hipStream_t stream) {
    const float* left  = (const float*)d_in[0];
    const float* right = (const float*)d_in[1];
    float* out = (float*)d_out;

    const int grid  = BB * CC * (HH / HT);   // 512
    const int block = 512;
    cost_vol_kernel<<<grid, block, 0, stream>>>(left, right, out);
}